// Round 7
// baseline (220.680 us; speedup 1.0000x reference)
//
#include <hip/hip_runtime.h>

#define BS 4
#define NF 512
#define HW 4096
#define C8 64
#define TI 64                       // i-rows per fused block
#define JC 64                       // j-chunk

typedef unsigned short bfu;                                    // raw bf16 bits
typedef __attribute__((ext_vector_type(8))) short bf16x8;      // MFMA A/B frag (4 VGPRs)
typedef __attribute__((ext_vector_type(4))) float f32x4;       // MFMA C/D frag

static __device__ __forceinline__ bfu f2bu(float v) {
    union { unsigned int u; float f; } c; c.f = v;
    unsigned int u = c.u;
    u = u + 0x7FFFu + ((u >> 16) & 1u);   // round-to-nearest-even
    return (bfu)(u >> 16);
}

// pack 2 f32 -> 2 bf16 (RNE), one instruction (T12 primitive; no builtin on gfx950)
static __device__ __forceinline__ unsigned int cvt_pk_bf16(float lo, float hi) {
    unsigned int r;
    asm("v_cvt_pk_bf16_f32 %0, %1, %2" : "=v"(r) : "v"(lo), "v"(hi));
    return r;
}

// async global->LDS, 16 B per lane (global_load_lds_dwordx4)
static __device__ __forceinline__ void gload16(const void* g, void* l) {
    __builtin_amdgcn_global_load_lds(
        (const __attribute__((address_space(1))) unsigned int*)g,
        (__attribute__((address_space(3))) unsigned int*)l,
        16, 0, 0);
}

// ---------------- k0_pre: x transpose (2048 blocks) + weight prep (640 blocks) merged ----------
__global__ __launch_bounds__(256) void k0_pre(const float* __restrict__ x, bfu* __restrict__ xt,
                                              const float* __restrict__ Wq, const float* __restrict__ bq,
                                              const float* __restrict__ Wk, const float* __restrict__ bk,
                                              const float* __restrict__ Wv, const float* __restrict__ bv,
                                              bfu* __restrict__ Wb, float* __restrict__ bcat)
{
    __shared__ float T[64][68];
    const int t   = threadIdx.x;
    const int bid = blockIdx.x;

    if (bid >= 2048) {                          // weight-prep blocks (old k0_w)
        const int o = bid - 2048;               // 0..639
        const float* src; float bias;
        if (o < 64)       { src = Wq + (size_t)o * NF;          bias = bq[o]; }
        else if (o < 128) { src = Wk + (size_t)(o - 64) * NF;   bias = bk[o - 64]; }
        else              { src = Wv + (size_t)(o - 128) * NF;  bias = bv[o - 128]; }
        float2 v = *(const float2*)(src + t * 2);
        Wb[(size_t)o * NF + t * 2 + 0] = f2bu(v.x);
        Wb[(size_t)o * NF + t * 2 + 1] = f2bu(v.y);
        if (t == 0) bcat[o] = bias;
        return;
    }

    const int n0 = (bid & 63) * 64;
    const int c0 = ((bid >> 6) & 7) * 64;
    const int b  = bid >> 9;

    #pragma unroll
    for (int u = 0; u < 4; u++) {
        int f4 = u * 256 + t;
        int cc = f4 >> 4;
        int n4 = (f4 & 15) << 2;
        float4 v = *(const float4*)(x + ((size_t)(b * NF + c0 + cc)) * HW + n0 + n4);
        *(float4*)&T[cc][n4 ^ (((cc >> 3) & 3) << 2)] = v;     // group-XOR by row bits 3..4
    }
    __syncthreads();
    #pragma unroll
    for (int u = 0; u < 2; u++) {
        int e8 = u * 256 + t;
        int nn = e8 >> 3;
        int c8 = (e8 & 7) << 3;
        union { int4 i4; bfu h[8]; } pk;
        #pragma unroll
        for (int q = 0; q < 8; q++)
            pk.h[q] = f2bu(T[c8 + q][nn ^ ((((c8 + q) >> 3) & 3) << 2)]);
        *(int4*)(xt + ((size_t)(b * HW + n0 + nn)) * NF + c0 + c8) = pk.i4;
    }
}

// ---------------- k1: Out[o][n] = Wb(640x512) . xt[b]^T, scatter into Qb/Kb/Vb ----------------
// R7: tile 128o x 64n (was 128x128). Grid (5,64,4)=1280 blocks, LDS 48 KB ->
// 3 blocks/CU resident, 5 blocks/CU of work: no 2.5-avg/2-resident straggler
// round. Q/K stored FRAGMENT-NATIVE: slot = quad*16 + mt*4 + r (a bijective
// channel permutation applied identically to Q and K is transparent to k23's
// S-MFMA — A/B positions pair by slot, so S = sum_c Q[c]K[c] regardless of
// order). Lane stores: 2x int4 (32 B contiguous) instead of 16x scattered int2.
__global__ __launch_bounds__(256) void k1_proj(const bfu* __restrict__ Wb, const float* __restrict__ bcat,
                                               const bfu* __restrict__ xt,
                                               bfu* __restrict__ Qb, bfu* __restrict__ Kb, bfu* __restrict__ Vb)
{
    __shared__ bfu As[2][128 * 64];     // 32 KB: o-rows 128 x c 64, dbuf
    __shared__ bfu Bs[2][64 * 64];      // 16 KB: n-rows 64 x c 64, dbuf
    const int t  = threadIdx.x;
    const int o0 = blockIdx.x * 128;
    const int n0 = blockIdx.y * 64;
    const int b  = blockIdx.z;
    const int lane = t & 63, wv = t >> 6;
    const int wm = wv & 1, wn = wv >> 1;            // o-half 64, n-half 32
    const int l15 = lane & 15, quad = lane >> 4;
    const int r7  = l15 & 7;
    const int sl0 = (quad ^ r7) * 8;                // swizzled slot, kk=0
    const int sl1 = ((quad + 4) ^ r7) * 8;          // swizzled slot, kk=32

    const int srow = t >> 3;                        // 0..31
    const int scolz = ((t & 7) ^ (srow & 7)) * 8;   // pre-swizzled source column

    const bfu* gA = Wb + ((size_t)(o0 + srow)) * NF + scolz;
    const bfu* gB = xt + ((size_t)(b * HW + n0 + srow)) * NF + scolz;

    f32x4 acc[4][2];
    #pragma unroll
    for (int m = 0; m < 4; m++)
        #pragma unroll
        for (int n = 0; n < 2; n++) acc[m][n] = (f32x4){0.f, 0.f, 0.f, 0.f};

#define K1_STAGE(buf, c0)                                                       \
    _Pragma("unroll")                                                           \
    for (int p = 0; p < 4; p++)                                                 \
        gload16(gA + (size_t)(p * 32) * NF + (c0), &As[buf][t * 8 + p * 2048]); \
    _Pragma("unroll")                                                           \
    for (int p = 0; p < 2; p++)                                                 \
        gload16(gB + (size_t)(p * 32) * NF + (c0), &Bs[buf][t * 8 + p * 2048]);

#define K1_COMPUTE(pc)                                                                      \
    {                                                                                       \
        bf16x8 Af0[4], Af1[4], Bf0[2], Bf1[2];                                              \
        _Pragma("unroll")                                                                   \
        for (int m = 0; m < 4; m++) {                                                       \
            const bfu* ar = &As[pc][(wm * 64 + m * 16 + l15) * 64];                         \
            Af0[m] = *(const bf16x8*)(ar + sl0);                                            \
            Af1[m] = *(const bf16x8*)(ar + sl1);                                            \
        }                                                                                   \
        _Pragma("unroll")                                                                   \
        for (int n = 0; n < 2; n++) {                                                       \
            const bfu* br = &Bs[pc][(wn * 32 + n * 16 + l15) * 64];                         \
            Bf0[n] = *(const bf16x8*)(br + sl0);                                            \
            Bf1[n] = *(const bf16x8*)(br + sl1);                                            \
        }                                                                                   \
        __builtin_amdgcn_s_setprio(1);                                                      \
        _Pragma("unroll")                                                                   \
        for (int m = 0; m < 4; m++)                                                         \
            _Pragma("unroll")                                                               \
            for (int n = 0; n < 2; n++) {                                                   \
                acc[m][n] = __builtin_amdgcn_mfma_f32_16x16x32_bf16(Af0[m], Bf0[n], acc[m][n], 0, 0, 0); \
                acc[m][n] = __builtin_amdgcn_mfma_f32_16x16x32_bf16(Af1[m], Bf1[n], acc[m][n], 0, 0, 0); \
            }                                                                               \
        __builtin_amdgcn_s_setprio(0);                                                      \
    }

    K1_STAGE(0, 0)                              // prologue: 6 vmem outstanding
    for (int it = 0; it < 7; it++) {
        const int pc = it & 1;
        K1_STAGE(pc ^ 1, (it + 1) * 64)         // +6 vmem -> 12
        asm volatile("s_waitcnt vmcnt(6)" ::: "memory");   // retire stage(it)
        __builtin_amdgcn_sched_barrier(0);
        __builtin_amdgcn_s_barrier();           // buf[pc] ready for all waves
        K1_COMPUTE(pc)
        __builtin_amdgcn_sched_barrier(0);
        __builtin_amdgcn_s_barrier();           // reads done -> restage ok
    }
    asm volatile("s_waitcnt vmcnt(0)" ::: "memory");
    __builtin_amdgcn_sched_barrier(0);
    __builtin_amdgcn_s_barrier();
    K1_COMPUTE(1)                               // c0 = 7 lives in buf 1
#undef K1_STAGE
#undef K1_COMPUTE

    if (o0 == 0) {
        // Q/K fragment-native: slot = quad*16 + mt*4 + r -> lane writes 32 B
        // contiguous as two int4. k23 reads slots quad*8(+32) identically for
        // Q and K -> S unchanged (bijective slot permutation is transparent).
        #pragma unroll
        for (int nt = 0; nt < 2; nt++) {
            int n = n0 + wn * 32 + nt * 16 + l15;
            float v[16];
            #pragma unroll
            for (int mt = 0; mt < 4; mt++)
                #pragma unroll
                for (int r = 0; r < 4; r++)
                    v[mt * 4 + r] = acc[mt][nt][r] + bcat[wm * 64 + mt * 16 + quad * 4 + r];
            int4 p0, p1;
            p0.x = (int)cvt_pk_bf16(v[0],  v[1]);  p0.y = (int)cvt_pk_bf16(v[2],  v[3]);
            p0.z = (int)cvt_pk_bf16(v[4],  v[5]);  p0.w = (int)cvt_pk_bf16(v[6],  v[7]);
            p1.x = (int)cvt_pk_bf16(v[8],  v[9]);  p1.y = (int)cvt_pk_bf16(v[10], v[11]);
            p1.z = (int)cvt_pk_bf16(v[12], v[13]); p1.w = (int)cvt_pk_bf16(v[14], v[15]);
            bfu* dst = (wm == 0 ? Qb : Kb) + ((size_t)(b * HW + n)) * C8 + quad * 16;
            *(int4*)dst       = p0;
            *(int4*)(dst + 8) = p1;
        }
    } else {
        #pragma unroll
        for (int mt = 0; mt < 4; mt++)
            #pragma unroll
            for (int nt = 0; nt < 2; nt++)
                #pragma unroll
                for (int r = 0; r < 4; r++) {
                    int go = o0 + wm * 64 + mt * 16 + quad * 4 + r;  // 128..639
                    int n  = n0 + wn * 32 + nt * 16 + l15;
                    float val = acc[mt][nt][r] + bcat[go];
                    Vb[((size_t)(b * NF + (go - 128))) * HW + n] = f2bu(val);
                }
    }
}

// ---------------- k23: fused scores + softmax-numerator + PV + residual ----------------
// R6 structure, UNCHANGED (123.5 us, MfmaUtil 30.4, conflicts 2.1e6): R4
// geometry (TI=64, JC=64, c-split 2, grid 512, 2 blocks/CU) with phases
// restructured so nothing serial sits between the barriers; exp/pack after B2;
// Ps slot-swizzled single buffer; both-sides Vs swizzle; counted vmcnt(6).
__global__ __launch_bounds__(512, 4) void k23_fused(const bfu* __restrict__ Kb, const bfu* __restrict__ Qb,
                                                    const bfu* __restrict__ Vb,
                                                    const float* __restrict__ x, const float* __restrict__ alpha,
                                                    float* __restrict__ out)
{
    __shared__ bfu   Vs[2][256 * 64];   // 2 x 32 KB, linear DMA dest; rows slot-swizzled
    __shared__ bfu   Ps[64 * 64];       // 8 KB P-tile [i][j], slot-swizzled, no pad
    __shared__ float LSum[8][2][16];
    __shared__ float Scale[TI];

    const int t = threadIdx.x;
    const int lane = t & 63, w = t >> 6;
    const int l15 = lane & 15, quad = lane >> 4;
    const int jq  = w & 3;              // S-role: j-subtile
    const int iqb = (w >> 2) * 32;      // S-role: 32-row i-slab (two 16-row subtiles)

    // XCD pinning: d&7 -> XCD; b = xcd>>1, cblk = xcd&1; i0 from d>>3.
    const int d    = blockIdx.x;        // 0..511
    const int xcd  = d & 7;
    const int b    = xcd >> 1;
    const int cblk = xcd & 1;           // which 256-channel half of V/out
    const int i0   = (d >> 3) * TI;     // 0..4032

    // persistent K fragments (B-side of S-MFMA), two i-subtiles
    const bfu* kp0 = Kb + ((size_t)(b * HW + i0 + iqb + l15)) * C8 + quad * 8;
    const bfu* kp1 = kp0 + (size_t)16 * C8;
    const bf16x8 Kf00 = *(const bf16x8*)kp0;
    const bf16x8 Kf01 = *(const bf16x8*)(kp0 + 32);
    const bf16x8 Kf10 = *(const bf16x8*)kp1;
    const bf16x8 Kf11 = *(const bf16x8*)(kp1 + 32);

    // V staging: thread t fills rows (t>>3)+64p at slot (t&7); global column
    // pre-swizzled (slot ^ row&7) so linear DMA dest gets the swizzled layout.
    const int srow = t >> 3, sslot = t & 7;
    const bfu* gV = Vb + ((size_t)(b * NF + cblk * 256 + srow)) * HW + ((sslot ^ (srow & 7)) * 8);

    // Q stream base (A-side of S-MFMA): j = jb + jq*16 + l15
    const bfu* qbase = Qb + ((size_t)(b * HW + jq * 16 + l15)) * C8 + quad * 8;

    const int r7  = l15 & 7;
    const int sl0 = (quad ^ r7) * 8;            // swizzled 16B slot, kk=0 (Vs rows & Ps rows both have row&7==l15&7)
    const int sl1 = ((quad + 4) ^ r7) * 8;      // kk=1
    // Ps write offset: col granule jq*16+quad*4 -> slot jq*2+(quad>>1), sub (quad&1)*4 elems
    const int pwz = ((jq * 2 + (quad >> 1)) ^ r7) * 8 + (quad & 1) * 4;

    f32x4 acc[2][4];
    #pragma unroll
    for (int mt = 0; mt < 2; mt++)
        #pragma unroll
        for (int nt = 0; nt < 4; nt++) acc[mt][nt] = (f32x4){0.f, 0.f, 0.f, 0.f};
    float rs0 = 0.f, rs1 = 0.f;
    bf16x8 Aq[2][2];                    // Q frag double-buffer [parity][half]

    // prologue: Q(0), stage(0) -> Vs[0], S(0) -> Ps.
    Aq[0][0] = *(const bf16x8*)qbase;
    Aq[0][1] = *(const bf16x8*)(qbase + 32);
    #pragma unroll
    for (int p = 0; p < 4; p++)
        gload16(gV + (size_t)(p * 64) * HW, &Vs[0][t * 8 + p * 4096]);
    {
        f32x4 s0 = (f32x4){0.f,0.f,0.f,0.f}, s1 = (f32x4){0.f,0.f,0.f,0.f};
        s0 = __builtin_amdgcn_mfma_f32_16x16x32_bf16(Aq[0][0], Kf00, s0, 0, 0, 0);
        s0 = __builtin_amdgcn_mfma_f32_16x16x32_bf16(Aq[0][1], Kf01, s0, 0, 0, 0);
        s1 = __builtin_amdgcn_mfma_f32_16x16x32_bf16(Aq[0][0], Kf10, s1, 0, 0, 0);
        s1 = __builtin_amdgcn_mfma_f32_16x16x32_bf16(Aq[0][1], Kf11, s1, 0, 0, 0);
        float e0 = __expf(s0[0]), e1 = __expf(s0[1]), e2 = __expf(s0[2]), e3 = __expf(s0[3]);
        float f0 = __expf(s1[0]), f1 = __expf(s1[1]), f2 = __expf(s1[2]), f3 = __expf(s1[3]);
        rs0 += (e0 + e1) + (e2 + e3);
        rs1 += (f0 + f1) + (f2 + f3);
        uint2 pk0, pk1;
        pk0.x = cvt_pk_bf16(e0, e1);  pk0.y = cvt_pk_bf16(e2, e3);
        pk1.x = cvt_pk_bf16(f0, f1);  pk1.y = cvt_pk_bf16(f2, f3);
        *(uint2*)(Ps + (iqb + l15)      * 64 + pwz) = pk0;
        *(uint2*)(Ps + (iqb + 16 + l15) * 64 + pwz) = pk1;
    }

// one pipelined chunk iteration; pc/pn compile-time parities (rule #20)
#define K23_ITER(q, pc, pn)                                                                    \
  {                                                                                            \
    const int jn = (((q) + 1) & 63) * JC;                                                      \
    /* prefetch Q(q+1) [2 vmem] BEFORE stage(q+1) [4 vmem] */                                  \
    {                                                                                          \
        const bfu* qpn = qbase + (size_t)jn * C8;                                              \
        Aq[pn][0] = *(const bf16x8*)qpn;                                                       \
        Aq[pn][1] = *(const bf16x8*)(qpn + 32);                                                \
    }                                                                                          \
    _Pragma("unroll")                                                                          \
    for (int p = 0; p < 4; p++)                                                                \
        gload16(gV + (size_t)(p * 64) * HW + jn, &Vs[pn][t * 8 + p * 4096]);                   \
    /* retire stage(q); Q(q+1)+stage(q+1) stay in flight; lgkm: prev Ps writes done */         \
    asm volatile("s_waitcnt vmcnt(6) lgkmcnt(0)" ::: "memory");                                \
    __builtin_amdgcn_sched_barrier(0);                                                         \
    __builtin_amdgcn_s_barrier();   /* B1: Vs[pc] staged, Ps(q) visible */                     \
    /* S-MFMAs for chunk q+1 first: register-only, results consumed after B2 */                \
    f32x4 s0 = (f32x4){0.f,0.f,0.f,0.f}, s1 = (f32x4){0.f,0.f,0.f,0.f};                        \
    if (jn) {                                                                                  \
        s0 = __builtin_amdgcn_mfma_f32_16x16x32_bf16(Aq[pn][0], Kf00, s0, 0, 0, 0);            \
        s0 = __builtin_amdgcn_mfma_f32_16x16x32_bf16(Aq[pn][1], Kf01, s0, 0, 0, 0);            \
        s1 = __builtin_amdgcn_mfma_f32_16x16x32_bf16(Aq[pn][0], Kf10, s1, 0, 0, 0);            \
        s1 = __builtin_amdgcn_mfma_f32_16x16x32_bf16(Aq[pn][1], Kf11, s1, 0, 0, 0);            \
    }                                                                                          \
    /* PV: hold V frags, stream Pf per nt (keeps VGPR ~115) */                                 \
    {                                                                                          \
        bf16x8 V0[2], V1[2];                                                                   \
        _Pragma("unroll")                                                                      \
        for (int mt = 0; mt < 2; mt++) {                                                       \
            const bfu* vrow = &Vs[pc][(w * 32 + mt * 16 + l15) * 64];                          \
            V0[mt] = *(const bf16x8*)(vrow + sl0);                                             \
            V1[mt] = *(const bf16x8*)(vrow + sl1);                                             \
        }                                                                                      \
        __builtin_amdgcn_s_setprio(1);                                                         \
        _Pragma("unroll")                                                                      \
        for (int nt = 0; nt < 4; nt++) {                                                       \
            const bfu* prow = Ps + (nt * 16 + l15) * 64;                                       \
            bf16x8 Pf0 = *(const bf16x8*)(prow + sl0);                                         \
            bf16x8 Pf1 = *(const bf16x8*)(prow + sl1);                                         \
            _Pragma("unroll")                                                                  \
            for (int mt = 0; mt < 2; mt++) {                                                   \
                acc[mt][nt] = __builtin_amdgcn_mfma_f32_16x16x32_bf16(V0[mt], Pf0, acc[mt][nt], 0, 0, 0); \
                acc[mt][nt] = __builtin_amdgcn_mfma_f32_16x16x32_bf16(V1[mt], Pf1, acc[mt][nt], 0, 0, 0); \
            }                                                                                  \
        }                                                                                      \
        __builtin_amdgcn_s_setprio(0);                                                         \
    }                                                                                          \
    asm volatile("s_waitcnt lgkmcnt(0)" ::: "memory");                                         \
    __builtin_amdgcn_sched_barrier(0);                                                         \
    __builtin_amdgcn_s_barrier();   /* B2: all Ps/Vs reads done -> writable/restageable */     \
    /* softmax finish for chunk q+1: off the inter-barrier path */                             \
    if (jn) {                                                                                  \
        float e0 = __expf(s0[0]), e1 = __expf(s0[1]), e2 = __expf(s0[2]), e3 = __expf(s0[3]);  \
        float f0 = __expf(s1[0]), f1 = __expf(s1[1]), f2 = __expf(s1[2]), f3 = __expf(s1[3]);  \
        rs0 += (e0 + e1) + (e2 + e3);                                                          \
        rs1 += (f0 + f1) + (f2 + f3);                                                          \
        uint2 pk0, pk1;                                                                        \
        pk0.x = cvt_pk_bf16(e0, e1);  pk0.y = cvt_pk_bf16(e2, e3);                             \
        pk1.x = cvt_pk_bf16(f0, f1);  pk1.y = cvt_pk_bf16(f2, f3);                             \
        *(uint2*)(Ps + (iqb + l15)      * 64 + pwz) = pk0;                                     \
        *(uint2*)(Ps + (iqb + 16 + l15) * 64 + pwz) = pk1;                                     \
    }                                                                                          \
  }

    for (int qq = 0; qq < 32; qq++) {
        K23_ITER(2 * qq,     0, 1)
        K23_ITER(2 * qq + 1, 1, 0)
    }
#undef K23_ITER

    // row-sum reduction: rs0/rs1 cover i = i0 + iqb + {0,16} + l15
    float sred0 = rs0, sred1 = rs1;
    sred0 += __shfl_xor(sred0, 16, 64);
    sred0 += __shfl_xor(sred0, 32, 64);
    sred1 += __shfl_xor(sred1, 16, 64);
    sred1 += __shfl_xor(sred1, 32, 64);
    if (quad == 0) { LSum[w][0][l15] = sred0; LSum[w][1][l15] = sred1; }
    __syncthreads();
    if (t < TI) {
        int u = t >> 5, s = (t >> 4) & 1, il = t & 15;
        float L = (LSum[u * 4 + 0][s][il] + LSum[u * 4 + 1][s][il])
                + (LSum[u * 4 + 2][s][il] + LSum[u * 4 + 3][s][il]);
        Scale[t] = alpha[0] / L;
    }
    __syncthreads();

    #pragma unroll
    for (int nt = 0; nt < 4; nt++) {
        float sc = Scale[nt * 16 + l15];
        int i = i0 + nt * 16 + l15;
        #pragma unroll
        for (int mt = 0; mt < 2; mt++)
            #pragma unroll
            for (int r = 0; r < 4; r++) {
                int c = cblk * 256 + w * 32 + mt * 16 + quad * 4 + r;
                size_t idx = ((size_t)(b * NF + c)) * HW + i;
                out[idx] = x[idx] + sc * acc[mt][nt][r];
            }
    }
}

extern "C" void kernel_launch(void* const* d_in, const int* in_sizes, int n_in,
                              void* d_out, int out_size, void* d_ws, size_t ws_size,
                              hipStream_t stream)
{
    const float* x     = (const float*)d_in[0];
    const float* Wq    = (const float*)d_in[1];
    const float* bq    = (const float*)d_in[2];
    const float* Wk    = (const float*)d_in[3];
    const float* bk    = (const float*)d_in[4];
    const float* Wv    = (const float*)d_in[5];
    const float* bv    = (const float*)d_in[6];
    const float* alpha = (const float*)d_in[7];
    float* out = (float*)d_out;

    char* ws = (char*)d_ws;
    bfu*   xt   = (bfu*)(ws);                                  // [0,16) MB : [b][n][c] bf16
    bfu*   Wb   = (bfu*)(ws + (16u << 20));                    // [16,~16.6) MB: [640][512] bf16
    float* bcat = (float*)(ws + (17u << 20));                  // 2.5 KB at 17 MB
    bfu*   Qb   = (bfu*)(ws + (18u << 20));                    // [18,20) MB : [b][n][64]
    bfu*   Kb   = (bfu*)(ws + (20u << 20));                    // [20,22) MB : [b][n][64]
    bfu*   Vb   = (bfu*)(ws + (22u << 20));                    // [22,38) MB : [b][c][n]  (16 MB)

    k0_pre<<<dim3(2048 + 640), 256, 0, stream>>>(x, xt, Wq, bq, Wk, bk, Wv, bv, Wb, bcat);
    k1_proj<<<dim3(5, HW / 64, BS), 256, 0, stream>>>(Wb, bcat, xt, Qb, Kb, Vb);
    k23_fused<<<dim3(HW / TI * BS * 2), 512, 0, stream>>>(Kb, Qb, Vb, x, alpha, out);
}